// Round 1
// baseline (2751.158 us; speedup 1.0000x reference)
//
#include <hip/hip_runtime.h>

#define HEADS 4
#define FDIM 128          // HEADS * HID
#define NEG_SLOPE 0.2f
#define SM_EPS 1e-16f

// ---------- helpers ----------

// Monotone order-preserving f32 -> u32 encoding (for atomicMax on floats).
__device__ __forceinline__ unsigned enc_f32(float f) {
  unsigned u = __float_as_uint(f);
  return (f >= 0.f) ? (u | 0x80000000u) : ~u;
}
__device__ __forceinline__ float dec_f32(unsigned u) {
  return (u & 0x80000000u) ? __uint_as_float(u ^ 0x80000000u)
                           : __uint_as_float(~u);
}
__device__ __forceinline__ float lrelu(float v) {
  return v >= 0.f ? v : NEG_SLOPE * v;
}

// ---------- generic zero fill ----------
__global__ void zero_kernel(float* __restrict__ p, long n) {
  long i = (long)blockIdx.x * blockDim.x + threadIdx.x;
  long stride = (long)gridDim.x * blockDim.x;
  for (; i < n; i += stride) p[i] = 0.f;
}

// ---------- dense linear: H[n,128] = X[n,128] @ W[128,128] ----------
#define ROWS_PER_BLOCK 8
__global__ void linear_kernel(const float* __restrict__ X,
                              const float* __restrict__ W,
                              float* __restrict__ H, int nrows) {
  __shared__ float xs[ROWS_PER_BLOCK][FDIM];
  int col = threadIdx.x;               // 128 threads
  int row0 = blockIdx.x * ROWS_PER_BLOCK;
  #pragma unroll
  for (int r = 0; r < ROWS_PER_BLOCK; ++r) {
    int row = row0 + r;
    xs[r][col] = (row < nrows) ? X[(long)row * FDIM + col] : 0.f;
  }
  __syncthreads();
  float acc[ROWS_PER_BLOCK];
  #pragma unroll
  for (int r = 0; r < ROWS_PER_BLOCK; ++r) acc[r] = 0.f;
  #pragma unroll 16
  for (int k = 0; k < FDIM; ++k) {
    float wv = W[k * FDIM + col];
    #pragma unroll
    for (int r = 0; r < ROWS_PER_BLOCK; ++r) acc[r] += xs[r][k] * wv;
  }
  #pragma unroll
  for (int r = 0; r < ROWS_PER_BLOCK; ++r) {
    int row = row0 + r;
    if (row < nrows) H[(long)row * FDIM + col] = acc[r];
  }
}

// ---------- per-node attention coefficients ----------
// a_s[n,h] = sum_c H[n,h,c]*att_s[h,c];  a_d likewise
__global__ void attn_coef_kernel(const float* __restrict__ H,
                                 const float* __restrict__ att_s,
                                 const float* __restrict__ att_d,
                                 float* __restrict__ a_s,
                                 float* __restrict__ a_d, int n) {
  int idx = blockIdx.x * blockDim.x + threadIdx.x;  // n*HEADS
  if (idx >= n * HEADS) return;
  int node = idx >> 2, head = idx & 3;
  const float4* hp = (const float4*)(H + (long)node * FDIM + head * 32);
  const float4* sp = (const float4*)(att_s + head * 32);
  const float4* dp = (const float4*)(att_d + head * 32);
  float ss = 0.f, sd = 0.f;
  #pragma unroll
  for (int c = 0; c < 8; ++c) {
    float4 v = hp[c], s4 = sp[c], d4 = dp[c];
    ss += v.x * s4.x + v.y * s4.y + v.z * s4.z + v.w * s4.w;
    sd += v.x * d4.x + v.y * d4.y + v.z * d4.z + v.w * d4.w;
  }
  a_s[idx] = ss;
  a_d[idx] = sd;
}

// ---------- edge pass 1: logits + segment max ----------
__global__ void edge_logits_kernel(const int* __restrict__ src,
                                   const int* __restrict__ dst,
                                   const float* __restrict__ a_s,
                                   const float* __restrict__ a_d,
                                   float* __restrict__ ebuf,
                                   unsigned* __restrict__ m_enc, int ne) {
  int i = blockIdx.x * blockDim.x + threadIdx.x;
  if (i >= ne) return;
  int s = src[i], d = dst[i];
  float4 vs = *(const float4*)(a_s + (long)s * HEADS);
  float4 vd = *(const float4*)(a_d + (long)d * HEADS);
  float4 ev;
  ev.x = lrelu(vs.x + vd.x);
  ev.y = lrelu(vs.y + vd.y);
  ev.z = lrelu(vs.z + vd.z);
  ev.w = lrelu(vs.w + vd.w);
  *(float4*)(ebuf + (long)i * HEADS) = ev;
  unsigned* mp = m_enc + (long)d * HEADS;
  atomicMax(&mp[0], enc_f32(ev.x));
  atomicMax(&mp[1], enc_f32(ev.y));
  atomicMax(&mp[2], enc_f32(ev.z));
  atomicMax(&mp[3], enc_f32(ev.w));
}

// ---------- edge pass 2: exp + segment sum ----------
__global__ void edge_exp_kernel(const int* __restrict__ dst,
                                float* __restrict__ ebuf,   // in: e, out: ex
                                const unsigned* __restrict__ m_enc,
                                float* __restrict__ ssum, int ne) {
  int i = blockIdx.x * blockDim.x + threadIdx.x;
  if (i >= ne) return;
  int d = dst[i];
  float4 ev = *(const float4*)(ebuf + (long)i * HEADS);
  const unsigned* mp = m_enc + (long)d * HEADS;
  float4 xv;
  xv.x = __expf(ev.x - dec_f32(mp[0]));
  xv.y = __expf(ev.y - dec_f32(mp[1]));
  xv.z = __expf(ev.z - dec_f32(mp[2]));
  xv.w = __expf(ev.w - dec_f32(mp[3]));
  *(float4*)(ebuf + (long)i * HEADS) = xv;
  float* sp = ssum + (long)d * HEADS;
  atomicAdd(&sp[0], xv.x);
  atomicAdd(&sp[1], xv.y);
  atomicAdd(&sp[2], xv.z);
  atomicAdd(&sp[3], xv.w);
}

// ---------- edge pass 3: alpha * h[src] scattered into out[dst] ----------
// one 64-lane wave per edge; lane handles channels c and c+64
__global__ void edge_aggr_kernel(const int* __restrict__ src,
                                 const int* __restrict__ dst,
                                 const float* __restrict__ H,
                                 const float* __restrict__ ex,
                                 const float* __restrict__ ssum,
                                 float* __restrict__ out, int ne) {
  int lane = threadIdx.x & 63;
  int e = blockIdx.x * (blockDim.x >> 6) + (threadIdx.x >> 6);
  if (e >= ne) return;
  int s = src[e], d = dst[e];
  int c0 = lane, c1 = lane + 64;
  int h0 = c0 >> 5, h1 = c1 >> 5;
  float al0 = ex[(long)e * HEADS + h0] / (ssum[(long)d * HEADS + h0] + SM_EPS);
  float al1 = ex[(long)e * HEADS + h1] / (ssum[(long)d * HEADS + h1] + SM_EPS);
  const float* hs = H + (long)s * FDIM;
  float* op = out + (long)d * FDIM;
  atomicAdd(&op[c0], al0 * hs[c0]);
  atomicAdd(&op[c1], al1 * hs[c1]);
}

// ---------- bias (+ optional SiLU) epilogue ----------
__global__ void bias_act_kernel(float* __restrict__ out,
                                const float* __restrict__ bias, long n,
                                int do_silu) {
  long i = (long)blockIdx.x * blockDim.x + threadIdx.x;
  if (i >= n) return;
  float v = out[i] + bias[i & (FDIM - 1)];
  if (do_silu) v = v / (1.f + __expf(-v));
  out[i] = v;
}

// ---------- DistMult decoder ----------
__global__ void decoder_kernel(const float* __restrict__ emb,
                               const float* __restrict__ rel_emb,
                               const int* __restrict__ hd,
                               const int* __restrict__ rl,
                               const int* __restrict__ tl,
                               float* __restrict__ out, int nq) {
  int lane = threadIdx.x & 63;
  int q = blockIdx.x * (blockDim.x >> 6) + (threadIdx.x >> 6);
  if (q >= nq) return;
  int h = hd[q], r = rl[q], t = tl[q];
  const float* eh = emb + (long)h * FDIM;
  const float* et = emb + (long)t * FDIM;
  const float* er = rel_emb + (long)r * FDIM;
  float acc = eh[lane] * er[lane] * et[lane] +
              eh[lane + 64] * er[lane + 64] * et[lane + 64];
  #pragma unroll
  for (int off = 32; off > 0; off >>= 1) acc += __shfl_down(acc, off, 64);
  if (lane == 0) out[q] = 1.f / (1.f + __expf(-acc));
}

// ---------- host side ----------
extern "C" void kernel_launch(void* const* d_in, const int* in_sizes, int n_in,
                              void* d_out, int out_size, void* d_ws,
                              size_t ws_size, hipStream_t stream) {
  const float* x    = (const float*)d_in[0];
  const int*   esrc = (const int*)d_in[1];
  const int*   edst = (const int*)d_in[2];
  const int*   hidx = (const int*)d_in[3];
  const int*   rel  = (const int*)d_in[4];
  const int*   tidx = (const int*)d_in[5];
  const float* W1   = (const float*)d_in[6];
  const float* b1   = (const float*)d_in[7];
  const float* as1  = (const float*)d_in[8];
  const float* ad1  = (const float*)d_in[9];
  const float* W2   = (const float*)d_in[10];
  const float* b2   = (const float*)d_in[11];
  const float* as2  = (const float*)d_in[12];
  const float* ad2  = (const float*)d_in[13];
  const float* remb = (const float*)d_in[14];
  float* out = (float*)d_out;

  const int N_ = in_sizes[0] / FDIM;
  const int E_ = in_sizes[1];
  const int Q_ = in_sizes[3];

  // workspace layout
  float*    h      = (float*)d_ws;            // N*128
  float*    agg    = h + (long)N_ * FDIM;     // N*128
  float*    a_s    = agg + (long)N_ * FDIM;   // N*4
  float*    a_d    = a_s + (long)N_ * HEADS;  // N*4
  unsigned* m_enc  = (unsigned*)(a_d + (long)N_ * HEADS);  // N*4
  float*    ssum   = (float*)(m_enc + (long)N_ * HEADS);   // N*4
  float*    ebuf   = ssum + (long)N_ * HEADS;               // E*4

  const int ZB = 1024;  // blocks for zero fills (grid-stride)

  for (int layer = 0; layer < 2; ++layer) {
    const float* Xin  = (layer == 0) ? x : agg;
    const float* W    = (layer == 0) ? W1 : W2;
    const float* bias = (layer == 0) ? b1 : b2;
    const float* atts = (layer == 0) ? as1 : as2;
    const float* attd = (layer == 0) ? ad1 : ad2;

    // h = Xin @ W
    linear_kernel<<<(N_ + ROWS_PER_BLOCK - 1) / ROWS_PER_BLOCK, FDIM, 0,
                    stream>>>(Xin, W, h, N_);
    // attention coefficients
    attn_coef_kernel<<<(N_ * HEADS + 255) / 256, 256, 0, stream>>>(
        h, atts, attd, a_s, a_d, N_);
    // zero m_enc (enc(-inf) < any finite enc, and 0 < any finite enc), ssum, agg
    zero_kernel<<<ZB, 256, 0, stream>>>((float*)m_enc, (long)N_ * HEADS);
    zero_kernel<<<ZB, 256, 0, stream>>>(ssum, (long)N_ * HEADS);
    zero_kernel<<<ZB, 256, 0, stream>>>(agg, (long)N_ * FDIM);
    // edge passes
    edge_logits_kernel<<<(E_ + 255) / 256, 256, 0, stream>>>(
        esrc, edst, a_s, a_d, ebuf, m_enc, E_);
    edge_exp_kernel<<<(E_ + 255) / 256, 256, 0, stream>>>(
        edst, ebuf, m_enc, ssum, E_);
    edge_aggr_kernel<<<(E_ + 3) / 4, 256, 0, stream>>>(
        esrc, edst, h, ebuf, ssum, agg, E_);
    // epilogue: bias (+ SiLU on layer 0)
    bias_act_kernel<<<((long)N_ * FDIM + 255) / 256, 256, 0, stream>>>(
        agg, bias, (long)N_ * FDIM, layer == 0 ? 1 : 0);
  }

  // DistMult decoder
  decoder_kernel<<<(Q_ + 3) / 4, 256, 0, stream>>>(agg, remb, hidx, rel, tidx,
                                                   out, Q_);
}

// Round 2
// 767.268 us; speedup vs baseline: 3.5857x; 3.5857x over previous
//
#include <hip/hip_runtime.h>

#define HEADS 4
#define FDIM 128          // HEADS * HID
#define NEG_SLOPE 0.2f
#define SM_EPS 1e-16f

__device__ __forceinline__ float lrelu(float v) {
  return v >= 0.f ? v : NEG_SLOPE * v;
}

// ---------- zero fill (ints) ----------
__global__ void zero_i_kernel(int* __restrict__ p, long n) {
  long i = (long)blockIdx.x * blockDim.x + threadIdx.x;
  long stride = (long)gridDim.x * blockDim.x;
  for (; i < n; i += stride) p[i] = 0;
}

// ---------- CSR build: degree histogram ----------
__global__ void hist_kernel(const int* __restrict__ dst, int* __restrict__ deg,
                            int ne) {
  int i = blockIdx.x * blockDim.x + threadIdx.x;
  if (i < ne) atomicAdd(&deg[dst[i]], 1);
}

// ---------- 3-phase exclusive scan over deg[n] -> rowptr[n+1] ----------
#define SCAN_BLOCK 256
#define SCAN_CHUNK 1024  // 4 elems / thread

__global__ void scan1_kernel(const int* __restrict__ deg,
                             int* __restrict__ partials, int n) {
  __shared__ int sdata[SCAN_BLOCK];
  int chunk0 = blockIdx.x * SCAN_CHUNK;
  int t = threadIdx.x;
  int sum = 0;
  #pragma unroll
  for (int j = 0; j < 4; ++j) {
    int idx = chunk0 + t * 4 + j;
    if (idx < n) sum += deg[idx];
  }
  sdata[t] = sum;
  __syncthreads();
  for (int off = SCAN_BLOCK / 2; off > 0; off >>= 1) {
    if (t < off) sdata[t] += sdata[t + off];
    __syncthreads();
  }
  if (t == 0) partials[blockIdx.x] = sdata[0];
}

__global__ void scan2_kernel(int* __restrict__ partials, int nb) {
  if (threadIdx.x == 0 && blockIdx.x == 0) {
    int run = 0;
    for (int i = 0; i < nb; ++i) {
      int v = partials[i];
      partials[i] = run;
      run += v;
    }
  }
}

__global__ void scan3_kernel(const int* __restrict__ deg,
                             const int* __restrict__ partials,
                             int* __restrict__ rowptr, int n) {
  __shared__ int sdata[SCAN_BLOCK];
  int chunk0 = blockIdx.x * SCAN_CHUNK;
  int t = threadIdx.x;
  int v[4];
  int sum = 0;
  #pragma unroll
  for (int j = 0; j < 4; ++j) {
    int idx = chunk0 + t * 4 + j;
    v[j] = (idx < n) ? deg[idx] : 0;
    sum += v[j];
  }
  sdata[t] = sum;
  __syncthreads();
  // inclusive Hillis-Steele scan over thread sums
  for (int off = 1; off < SCAN_BLOCK; off <<= 1) {
    int val = sdata[t];
    int add = (t >= off) ? sdata[t - off] : 0;
    __syncthreads();
    sdata[t] = val + add;
    __syncthreads();
  }
  int ex = (t > 0) ? sdata[t - 1] : 0;
  int base = partials[blockIdx.x] + ex;
  #pragma unroll
  for (int j = 0; j < 4; ++j) {
    int idx = chunk0 + t * 4 + j;
    if (idx < n) {
      rowptr[idx] = base;
      base += v[j];
      if (idx == n - 1) rowptr[n] = base;
    }
  }
}

// ---------- CSR build: scatter src indices into dst-sorted order ----------
__global__ void scatter_kernel(const int* __restrict__ src,
                               const int* __restrict__ dst,
                               const int* __restrict__ rowptr,
                               int* __restrict__ fill, int* __restrict__ col,
                               int ne) {
  int i = blockIdx.x * blockDim.x + threadIdx.x;
  if (i >= ne) return;
  int d = dst[i];
  int pos = rowptr[d] + atomicAdd(&fill[d], 1);
  col[pos] = src[i];
}

// ---------- dense linear + fused attention coefficients ----------
// H[n,128] = X[n,128] @ W[128,128];  a_s[n,h] = <H[n,h,:], att_s[h,:]>
#define ROWS_PER_BLOCK 8
__global__ void linear_attn_kernel(const float* __restrict__ X,
                                   const float* __restrict__ W,
                                   const float* __restrict__ att_s,
                                   const float* __restrict__ att_d,
                                   float* __restrict__ H,
                                   float* __restrict__ a_s,
                                   float* __restrict__ a_d, int nrows) {
  __shared__ float xs[ROWS_PER_BLOCK][FDIM];
  int col = threadIdx.x;  // 128 threads
  int row0 = blockIdx.x * ROWS_PER_BLOCK;
  #pragma unroll
  for (int r = 0; r < ROWS_PER_BLOCK; ++r) {
    int row = row0 + r;
    xs[r][col] = (row < nrows) ? X[(long)row * FDIM + col] : 0.f;
  }
  __syncthreads();
  float acc[ROWS_PER_BLOCK];
  #pragma unroll
  for (int r = 0; r < ROWS_PER_BLOCK; ++r) acc[r] = 0.f;
  #pragma unroll 16
  for (int k = 0; k < FDIM; ++k) {
    float wv = W[k * FDIM + col];
    #pragma unroll
    for (int r = 0; r < ROWS_PER_BLOCK; ++r) acc[r] += xs[r][k] * wv;
  }
  float ws = att_s[col], wd = att_d[col];
  #pragma unroll
  for (int r = 0; r < ROWS_PER_BLOCK; ++r) {
    int row = row0 + r;
    if (row < nrows) H[(long)row * FDIM + col] = acc[r];
    // reduce acc[r]*att within each 32-lane head group (groups are
    // 32-aligned, so xor-shuffles with off<32 stay inside the group)
    float vs = acc[r] * ws, vd = acc[r] * wd;
    #pragma unroll
    for (int off = 16; off >= 1; off >>= 1) {
      vs += __shfl_xor(vs, off, 64);
      vd += __shfl_xor(vd, off, 64);
    }
    if ((col & 31) == 0 && row < nrows) {
      a_s[(long)row * HEADS + (col >> 5)] = vs;
      a_d[(long)row * HEADS + (col >> 5)] = vd;
    }
  }
}

// ---------- fused GAT aggregation: one wave per destination node ----------
// No max-shift: logits are O(+-10), exp cannot overflow in f32, and softmax
// is shift-invariant, so result matches the reference to ~1 ulp.
__global__ void gat_gather_kernel(const int* __restrict__ rowptr,
                                  const int* __restrict__ col,
                                  const float* __restrict__ H,
                                  const float* __restrict__ a_s,
                                  const float* __restrict__ a_d,
                                  const float* __restrict__ bias,
                                  float* __restrict__ out, int n,
                                  int do_silu) {
  int lane = threadIdx.x & 63;
  int node = blockIdx.x * (blockDim.x >> 6) + (threadIdx.x >> 6);
  if (node >= n) return;
  int beg = rowptr[node], end = rowptr[node + 1];
  float4 ad4 = *(const float4*)(a_d + (long)node * HEADS);
  // lane owns channels c0=lane (heads 0/1) and c1=lane+64 (heads 2/3)
  bool lo = lane < 32;
  float adA = lo ? ad4.x : ad4.y;
  float adB = lo ? ad4.z : ad4.w;
  float acc0 = 0.f, acc1 = 0.f, s0 = 0.f, s1 = 0.f;
  for (int i = beg; i < end; ++i) {
    int s = col[i];  // uniform across wave
    float4 as4 = *(const float4*)(a_s + (long)s * HEADS);
    float eA = lrelu((lo ? as4.x : as4.y) + adA);
    float eB = lrelu((lo ? as4.z : as4.w) + adB);
    float pA = __expf(eA);
    float pB = __expf(eB);
    const float* hs = H + (long)s * FDIM;
    acc0 += pA * hs[lane];
    acc1 += pB * hs[lane + 64];
    s0 += pA;
    s1 += pB;
  }
  float o0 = acc0 / (s0 + SM_EPS) + bias[lane];
  float o1 = acc1 / (s1 + SM_EPS) + bias[lane + 64];
  if (do_silu) {
    o0 = o0 / (1.f + __expf(-o0));
    o1 = o1 / (1.f + __expf(-o1));
  }
  out[(long)node * FDIM + lane] = o0;
  out[(long)node * FDIM + lane + 64] = o1;
}

// ---------- DistMult decoder ----------
__global__ void decoder_kernel(const float* __restrict__ emb,
                               const float* __restrict__ rel_emb,
                               const int* __restrict__ hd,
                               const int* __restrict__ rl,
                               const int* __restrict__ tl,
                               float* __restrict__ out, int nq) {
  int lane = threadIdx.x & 63;
  int q = blockIdx.x * (blockDim.x >> 6) + (threadIdx.x >> 6);
  if (q >= nq) return;
  int h = hd[q], r = rl[q], t = tl[q];
  const float* eh = emb + (long)h * FDIM;
  const float* et = emb + (long)t * FDIM;
  const float* er = rel_emb + (long)r * FDIM;
  float acc = eh[lane] * er[lane] * et[lane] +
              eh[lane + 64] * er[lane + 64] * et[lane + 64];
  #pragma unroll
  for (int off = 32; off > 0; off >>= 1) acc += __shfl_down(acc, off, 64);
  if (lane == 0) out[q] = 1.f / (1.f + __expf(-acc));
}

// ---------- host side ----------
extern "C" void kernel_launch(void* const* d_in, const int* in_sizes, int n_in,
                              void* d_out, int out_size, void* d_ws,
                              size_t ws_size, hipStream_t stream) {
  const float* x    = (const float*)d_in[0];
  const int*   esrc = (const int*)d_in[1];
  const int*   edst = (const int*)d_in[2];
  const int*   hidx = (const int*)d_in[3];
  const int*   rel  = (const int*)d_in[4];
  const int*   tidx = (const int*)d_in[5];
  const float* W1   = (const float*)d_in[6];
  const float* b1   = (const float*)d_in[7];
  const float* as1  = (const float*)d_in[8];
  const float* ad1  = (const float*)d_in[9];
  const float* W2   = (const float*)d_in[10];
  const float* b2   = (const float*)d_in[11];
  const float* as2  = (const float*)d_in[12];
  const float* ad2  = (const float*)d_in[13];
  const float* remb = (const float*)d_in[14];
  float* out = (float*)d_out;

  const int N_ = in_sizes[0] / FDIM;
  const int E_ = in_sizes[1];
  const int Q_ = in_sizes[3];

  // workspace layout (all 4-byte elems)
  float* h       = (float*)d_ws;                    // N*128
  float* emb     = h + (long)N_ * FDIM;             // N*128
  float* a_s     = emb + (long)N_ * FDIM;           // N*4
  float* a_d     = a_s + (long)N_ * HEADS;          // N*4
  int*   deg     = (int*)(a_d + (long)N_ * HEADS);  // N
  int*   fill    = deg + N_;                        // N
  int*   rowptr  = fill + N_;                       // N+1
  int*   partials= rowptr + N_ + 1;                 // <=256
  int*   colsrc  = partials + 256;                  // E

  // ---- build CSR (dst-sorted src list), reused by both layers ----
  zero_i_kernel<<<512, 256, 0, stream>>>(deg, 2L * N_);  // deg + fill
  hist_kernel<<<(E_ + 255) / 256, 256, 0, stream>>>(edst, deg, E_);
  int nb = (N_ + SCAN_CHUNK - 1) / SCAN_CHUNK;
  scan1_kernel<<<nb, SCAN_BLOCK, 0, stream>>>(deg, partials, N_);
  scan2_kernel<<<1, 64, 0, stream>>>(partials, nb);
  scan3_kernel<<<nb, SCAN_BLOCK, 0, stream>>>(deg, partials, rowptr, N_);
  scatter_kernel<<<(E_ + 255) / 256, 256, 0, stream>>>(esrc, edst, rowptr,
                                                       fill, colsrc, E_);

  for (int layer = 0; layer < 2; ++layer) {
    const float* Xin  = (layer == 0) ? x : emb;
    const float* W    = (layer == 0) ? W1 : W2;
    const float* bias = (layer == 0) ? b1 : b2;
    const float* atts = (layer == 0) ? as1 : as2;
    const float* attd = (layer == 0) ? ad1 : ad2;

    linear_attn_kernel<<<(N_ + ROWS_PER_BLOCK - 1) / ROWS_PER_BLOCK, FDIM, 0,
                         stream>>>(Xin, W, atts, attd, h, a_s, a_d, N_);
    gat_gather_kernel<<<(N_ + 3) / 4, 256, 0, stream>>>(
        rowptr, colsrc, h, a_s, a_d, bias, emb, N_, layer == 0 ? 1 : 0);
  }

  decoder_kernel<<<(Q_ + 3) / 4, 256, 0, stream>>>(emb, remb, hidx, rel, tidx,
                                                   out, Q_);
}

// Round 3
// 554.343 us; speedup vs baseline: 4.9629x; 1.3841x over previous
//
#include <hip/hip_runtime.h>
#include <hip/hip_fp16.h>

#define HEADS 4
#define FDIM 128          // HEADS * HID
#define NEG_SLOPE 0.2f
#define SM_EPS 1e-16f

__device__ __forceinline__ float lrelu(float v) {
  return v >= 0.f ? v : NEG_SLOPE * v;
}

// ---------- zero fill (ints) ----------
__global__ void zero_i_kernel(int* __restrict__ p, long n) {
  long i = (long)blockIdx.x * blockDim.x + threadIdx.x;
  long stride = (long)gridDim.x * blockDim.x;
  for (; i < n; i += stride) p[i] = 0;
}

// ---------- CSR build: degree histogram ----------
__global__ void hist_kernel(const int* __restrict__ dst, int* __restrict__ deg,
                            int ne) {
  int i = blockIdx.x * blockDim.x + threadIdx.x;
  if (i < ne) atomicAdd(&deg[dst[i]], 1);
}

// ---------- 3-phase exclusive scan over deg[n] -> rowptr[n+1] ----------
#define SCAN_BLOCK 256
#define SCAN_CHUNK 1024  // 4 elems / thread

__global__ void scan1_kernel(const int* __restrict__ deg,
                             int* __restrict__ partials, int n) {
  __shared__ int sdata[SCAN_BLOCK];
  int chunk0 = blockIdx.x * SCAN_CHUNK;
  int t = threadIdx.x;
  int sum = 0;
  #pragma unroll
  for (int j = 0; j < 4; ++j) {
    int idx = chunk0 + t * 4 + j;
    if (idx < n) sum += deg[idx];
  }
  sdata[t] = sum;
  __syncthreads();
  for (int off = SCAN_BLOCK / 2; off > 0; off >>= 1) {
    if (t < off) sdata[t] += sdata[t + off];
    __syncthreads();
  }
  if (t == 0) partials[blockIdx.x] = sdata[0];
}

__global__ void scan2_kernel(int* __restrict__ partials, int nb) {
  if (threadIdx.x == 0 && blockIdx.x == 0) {
    int run = 0;
    for (int i = 0; i < nb; ++i) {
      int v = partials[i];
      partials[i] = run;
      run += v;
    }
  }
}

__global__ void scan3_kernel(const int* __restrict__ deg,
                             const int* __restrict__ partials,
                             int* __restrict__ rowptr, int n) {
  __shared__ int sdata[SCAN_BLOCK];
  int chunk0 = blockIdx.x * SCAN_CHUNK;
  int t = threadIdx.x;
  int v[4];
  int sum = 0;
  #pragma unroll
  for (int j = 0; j < 4; ++j) {
    int idx = chunk0 + t * 4 + j;
    v[j] = (idx < n) ? deg[idx] : 0;
    sum += v[j];
  }
  sdata[t] = sum;
  __syncthreads();
  for (int off = 1; off < SCAN_BLOCK; off <<= 1) {
    int val = sdata[t];
    int add = (t >= off) ? sdata[t - off] : 0;
    __syncthreads();
    sdata[t] = val + add;
    __syncthreads();
  }
  int ex = (t > 0) ? sdata[t - 1] : 0;
  int base = partials[blockIdx.x] + ex;
  #pragma unroll
  for (int j = 0; j < 4; ++j) {
    int idx = chunk0 + t * 4 + j;
    if (idx < n) {
      rowptr[idx] = base;
      base += v[j];
      if (idx == n - 1) rowptr[n] = base;
    }
  }
}

// ---------- CSR build: scatter src indices into dst-sorted order ----------
__global__ void scatter_kernel(const int* __restrict__ src,
                               const int* __restrict__ dst,
                               const int* __restrict__ rowptr,
                               int* __restrict__ fill, int* __restrict__ col,
                               int ne) {
  int i = blockIdx.x * blockDim.x + threadIdx.x;
  if (i >= ne) return;
  int d = dst[i];
  int pos = rowptr[d] + atomicAdd(&fill[d], 1);
  col[pos] = src[i];
}

// ---------- dense linear + fused attention coefficients ----------
// Hh[n,128] (fp16) = X[n,128] @ W[128,128];  a_s[n,h] = <H[n,h,:], att_s[h,:]>
#define ROWS_PER_BLOCK 8
__global__ void linear_attn_kernel(const float* __restrict__ X,
                                   const float* __restrict__ W,
                                   const float* __restrict__ att_s,
                                   const float* __restrict__ att_d,
                                   __half* __restrict__ Hh,
                                   float* __restrict__ a_s,
                                   float* __restrict__ a_d, int nrows) {
  __shared__ float xs[ROWS_PER_BLOCK][FDIM];
  int col = threadIdx.x;  // 128 threads
  int row0 = blockIdx.x * ROWS_PER_BLOCK;
  #pragma unroll
  for (int r = 0; r < ROWS_PER_BLOCK; ++r) {
    int row = row0 + r;
    xs[r][col] = (row < nrows) ? X[(long)row * FDIM + col] : 0.f;
  }
  __syncthreads();
  float acc[ROWS_PER_BLOCK];
  #pragma unroll
  for (int r = 0; r < ROWS_PER_BLOCK; ++r) acc[r] = 0.f;
  #pragma unroll 16
  for (int k = 0; k < FDIM; ++k) {
    float wv = W[k * FDIM + col];
    #pragma unroll
    for (int r = 0; r < ROWS_PER_BLOCK; ++r) acc[r] += xs[r][k] * wv;
  }
  float ws = att_s[col], wd = att_d[col];
  #pragma unroll
  for (int r = 0; r < ROWS_PER_BLOCK; ++r) {
    int row = row0 + r;
    if (row < nrows) Hh[(long)row * FDIM + col] = __float2half(acc[r]);
    float vs = acc[r] * ws, vd = acc[r] * wd;
    #pragma unroll
    for (int off = 16; off >= 1; off >>= 1) {
      vs += __shfl_xor(vs, off, 64);
      vd += __shfl_xor(vd, off, 64);
    }
    if ((col & 31) == 0 && row < nrows) {
      a_s[(long)row * HEADS + (col >> 5)] = vs;
      a_d[(long)row * HEADS + (col >> 5)] = vd;
    }
  }
}

// ---------- fused GAT aggregation: one wave per destination node ----------
// Lane owns channels {2*lane, 2*lane+1} (same head h = lane>>4), so one exp
// per lane per edge and the softmax denominator is lane-local.
// 4-way unrolled: 4 col + 4 a_s + 4 H loads in flight per wave.
__global__ void gat_gather_kernel(const int* __restrict__ rowptr,
                                  const int* __restrict__ col,
                                  const __half2* __restrict__ Hh,  // [n][64]
                                  const float* __restrict__ a_s,
                                  const float* __restrict__ a_d,
                                  const float* __restrict__ bias,
                                  float* __restrict__ out,
                                  __half2* __restrict__ out_h,  // may be null
                                  int n, int do_silu) {
  int lane = threadIdx.x & 63;
  int node = blockIdx.x * (blockDim.x >> 6) + (threadIdx.x >> 6);
  if (node >= n) return;
  int beg = rowptr[node], end = rowptr[node + 1];
  int head = lane >> 4;
  float ad = a_d[(long)node * HEADS + head];
  float acc0 = 0.f, acc1 = 0.f, ssum = 0.f;
  int i = beg;
  for (; i + 4 <= end; i += 4) {
    int s0 = col[i], s1 = col[i + 1], s2 = col[i + 2], s3 = col[i + 3];
    float as0 = a_s[(long)s0 * HEADS + head];
    float as1 = a_s[(long)s1 * HEADS + head];
    float as2 = a_s[(long)s2 * HEADS + head];
    float as3 = a_s[(long)s3 * HEADS + head];
    __half2 h0 = Hh[(long)s0 * 64 + lane];
    __half2 h1 = Hh[(long)s1 * 64 + lane];
    __half2 h2 = Hh[(long)s2 * 64 + lane];
    __half2 h3 = Hh[(long)s3 * 64 + lane];
    float p0 = __expf(lrelu(as0 + ad));
    float p1 = __expf(lrelu(as1 + ad));
    float p2 = __expf(lrelu(as2 + ad));
    float p3 = __expf(lrelu(as3 + ad));
    float2 f0 = __half22float2(h0), f1 = __half22float2(h1);
    float2 f2 = __half22float2(h2), f3 = __half22float2(h3);
    acc0 += p0 * f0.x + p1 * f1.x + p2 * f2.x + p3 * f3.x;
    acc1 += p0 * f0.y + p1 * f1.y + p2 * f2.y + p3 * f3.y;
    ssum += p0 + p1 + p2 + p3;
  }
  for (; i < end; ++i) {
    int s = col[i];
    float as = a_s[(long)s * HEADS + head];
    __half2 hv = Hh[(long)s * 64 + lane];
    float p = __expf(lrelu(as + ad));
    float2 f = __half22float2(hv);
    acc0 += p * f.x;
    acc1 += p * f.y;
    ssum += p;
  }
  float inv = 1.f / (ssum + SM_EPS);
  float2 b2 = *(const float2*)(bias + 2 * lane);
  float o0 = acc0 * inv + b2.x;
  float o1 = acc1 * inv + b2.y;
  if (do_silu) {
    o0 = o0 / (1.f + __expf(-o0));
    o1 = o1 / (1.f + __expf(-o1));
  }
  *(float2*)(out + (long)node * FDIM + 2 * lane) = make_float2(o0, o1);
  if (out_h) out_h[(long)node * 64 + lane] = __floats2half2_rn(o0, o1);
}

// ---------- DistMult decoder (fp16 embeddings, f32 rel) ----------
__global__ void decoder_kernel(const __half2* __restrict__ emb_h,  // [n][64]
                               const float* __restrict__ rel_emb,
                               const int* __restrict__ hd,
                               const int* __restrict__ rl,
                               const int* __restrict__ tl,
                               float* __restrict__ out, int nq) {
  int lane = threadIdx.x & 63;
  int q = blockIdx.x * (blockDim.x >> 6) + (threadIdx.x >> 6);
  if (q >= nq) return;
  int h = hd[q], r = rl[q], t = tl[q];
  float2 eh = __half22float2(emb_h[(long)h * 64 + lane]);
  float2 et = __half22float2(emb_h[(long)t * 64 + lane]);
  float2 er = *(const float2*)(rel_emb + (long)r * FDIM + 2 * lane);
  float acc = eh.x * er.x * et.x + eh.y * er.y * et.y;
  #pragma unroll
  for (int off = 32; off > 0; off >>= 1) acc += __shfl_down(acc, off, 64);
  if (lane == 0) out[q] = 1.f / (1.f + __expf(-acc));
}

// ---------- host side ----------
extern "C" void kernel_launch(void* const* d_in, const int* in_sizes, int n_in,
                              void* d_out, int out_size, void* d_ws,
                              size_t ws_size, hipStream_t stream) {
  const float* x    = (const float*)d_in[0];
  const int*   esrc = (const int*)d_in[1];
  const int*   edst = (const int*)d_in[2];
  const int*   hidx = (const int*)d_in[3];
  const int*   rel  = (const int*)d_in[4];
  const int*   tidx = (const int*)d_in[5];
  const float* W1   = (const float*)d_in[6];
  const float* b1   = (const float*)d_in[7];
  const float* as1  = (const float*)d_in[8];
  const float* ad1  = (const float*)d_in[9];
  const float* W2   = (const float*)d_in[10];
  const float* b2   = (const float*)d_in[11];
  const float* as2  = (const float*)d_in[12];
  const float* ad2  = (const float*)d_in[13];
  const float* remb = (const float*)d_in[14];
  float* out = (float*)d_out;

  const int N_ = in_sizes[0] / FDIM;
  const int E_ = in_sizes[1];
  const int Q_ = in_sizes[3];

  // workspace layout
  float*   emb    = (float*)d_ws;                    // N*128 f32
  __half*  Hh     = (__half*)(emb + (long)N_ * FDIM);  // N*128 fp16
  __half*  emb_h  = Hh + (long)N_ * FDIM;              // N*128 fp16
  float*   a_s    = (float*)(emb_h + (long)N_ * FDIM); // N*4
  float*   a_d    = a_s + (long)N_ * HEADS;            // N*4
  int*     deg    = (int*)(a_d + (long)N_ * HEADS);    // N
  int*     fill   = deg + N_;                          // N
  int*     rowptr = fill + N_;                         // N+1
  int*     partials = rowptr + N_ + 1;                 // <=256
  int*     colsrc = partials + 256;                    // E

  // ---- build CSR (dst-sorted src list), reused by both layers ----
  zero_i_kernel<<<512, 256, 0, stream>>>(deg, 2L * N_);  // deg + fill
  hist_kernel<<<(E_ + 255) / 256, 256, 0, stream>>>(edst, deg, E_);
  int nb = (N_ + SCAN_CHUNK - 1) / SCAN_CHUNK;
  scan1_kernel<<<nb, SCAN_BLOCK, 0, stream>>>(deg, partials, N_);
  scan2_kernel<<<1, 64, 0, stream>>>(partials, nb);
  scan3_kernel<<<nb, SCAN_BLOCK, 0, stream>>>(deg, partials, rowptr, N_);
  scatter_kernel<<<(E_ + 255) / 256, 256, 0, stream>>>(esrc, edst, rowptr,
                                                       fill, colsrc, E_);

  for (int layer = 0; layer < 2; ++layer) {
    const float* Xin  = (layer == 0) ? x : emb;
    const float* W    = (layer == 0) ? W1 : W2;
    const float* bias = (layer == 0) ? b1 : b2;
    const float* atts = (layer == 0) ? as1 : as2;
    const float* attd = (layer == 0) ? ad1 : ad2;

    linear_attn_kernel<<<(N_ + ROWS_PER_BLOCK - 1) / ROWS_PER_BLOCK, FDIM, 0,
                         stream>>>(Xin, W, atts, attd, Hh, a_s, a_d, N_);
    gat_gather_kernel<<<(N_ + 3) / 4, 256, 0, stream>>>(
        rowptr, colsrc, (const __half2*)Hh, a_s, a_d, bias, emb,
        (layer == 1) ? (__half2*)emb_h : (__half2*)nullptr, N_,
        layer == 0 ? 1 : 0);
  }

  decoder_kernel<<<(Q_ + 3) / 4, 256, 0, stream>>>(
      (const __half2*)emb_h, remb, hidx, rel, tidx, out, Q_);
}

// Round 4
// 470.056 us; speedup vs baseline: 5.8528x; 1.1793x over previous
//
#include <hip/hip_runtime.h>
#include <hip/hip_fp16.h>

#define HEADS 4
#define FDIM 128          // HEADS * HID
#define NEG_SLOPE 0.2f
#define SM_EPS 1e-16f

typedef _Float16 f16x8 __attribute__((ext_vector_type(8)));
typedef float f32x4 __attribute__((ext_vector_type(4)));

__device__ __forceinline__ float lrelu(float v) {
  return v >= 0.f ? v : NEG_SLOPE * v;
}

// ---------- zero fill (ints) ----------
__global__ void zero_i_kernel(int* __restrict__ p, long n) {
  long i = (long)blockIdx.x * blockDim.x + threadIdx.x;
  long stride = (long)gridDim.x * blockDim.x;
  for (; i < n; i += stride) p[i] = 0;
}

// ---------- CSR build: degree histogram ----------
__global__ void hist_kernel(const int* __restrict__ dst, int* __restrict__ deg,
                            int ne) {
  int i = blockIdx.x * blockDim.x + threadIdx.x;
  if (i < ne) atomicAdd(&deg[dst[i]], 1);
}

// ---------- 3-phase exclusive scan over deg[n] -> rowptr[n+1] ----------
#define SCAN_BLOCK 256
#define SCAN_CHUNK 1024  // 4 elems / thread

__global__ void scan1_kernel(const int* __restrict__ deg,
                             int* __restrict__ partials, int n) {
  __shared__ int sdata[SCAN_BLOCK];
  int chunk0 = blockIdx.x * SCAN_CHUNK;
  int t = threadIdx.x;
  int sum = 0;
  #pragma unroll
  for (int j = 0; j < 4; ++j) {
    int idx = chunk0 + t * 4 + j;
    if (idx < n) sum += deg[idx];
  }
  sdata[t] = sum;
  __syncthreads();
  for (int off = SCAN_BLOCK / 2; off > 0; off >>= 1) {
    if (t < off) sdata[t] += sdata[t + off];
    __syncthreads();
  }
  if (t == 0) partials[blockIdx.x] = sdata[0];
}

__global__ void scan2_kernel(int* __restrict__ partials, int nb) {
  if (threadIdx.x == 0 && blockIdx.x == 0) {
    int run = 0;
    for (int i = 0; i < nb; ++i) {
      int v = partials[i];
      partials[i] = run;
      run += v;
    }
  }
}

__global__ void scan3_kernel(const int* __restrict__ deg,
                             const int* __restrict__ partials,
                             int* __restrict__ rowptr, int n) {
  __shared__ int sdata[SCAN_BLOCK];
  int chunk0 = blockIdx.x * SCAN_CHUNK;
  int t = threadIdx.x;
  int v[4];
  int sum = 0;
  #pragma unroll
  for (int j = 0; j < 4; ++j) {
    int idx = chunk0 + t * 4 + j;
    v[j] = (idx < n) ? deg[idx] : 0;
    sum += v[j];
  }
  sdata[t] = sum;
  __syncthreads();
  for (int off = 1; off < SCAN_BLOCK; off <<= 1) {
    int val = sdata[t];
    int add = (t >= off) ? sdata[t - off] : 0;
    __syncthreads();
    sdata[t] = val + add;
    __syncthreads();
  }
  int ex = (t > 0) ? sdata[t - 1] : 0;
  int base = partials[blockIdx.x] + ex;
  #pragma unroll
  for (int j = 0; j < 4; ++j) {
    int idx = chunk0 + t * 4 + j;
    if (idx < n) {
      rowptr[idx] = base;
      base += v[j];
      if (idx == n - 1) rowptr[n] = base;
    }
  }
}

// ---------- CSR build: scatter src indices into dst-sorted order ----------
__global__ void scatter_kernel(const int* __restrict__ src,
                               const int* __restrict__ dst,
                               const int* __restrict__ rowptr,
                               int* __restrict__ fill, int* __restrict__ col,
                               int ne) {
  int i = blockIdx.x * blockDim.x + threadIdx.x;
  if (i >= ne) return;
  int d = dst[i];
  int pos = rowptr[d] + atomicAdd(&fill[d], 1);
  __builtin_nontemporal_store(src[i], &col[pos]);
}

// ---------- MFMA split-fp16 linear: Hh[n,128] = f16(X[n,128] @ W[128,128]) ----------
// Split precision: x = xh + xl, w = wh + wl (fp16 halves); f32-accurate via
// xh*wh + xh*wl + xl*wh MFMA chains (f32 accumulator). W staged to LDS
// transposed [n][k], fp16-split, XOR-swizzled so B-frags are single
// conflict-free ds_read_b128; B-frags then live in registers across a
// grid-stride loop over M tiles.
__global__ __launch_bounds__(256) void mfma_linear_kernel(
    const float* __restrict__ X, const float* __restrict__ W,
    __half* __restrict__ Hh, int nrows, int ntiles) {
  __shared__ _Float16 WtH[128 * 128];  // 32 KB
  __shared__ _Float16 WtL[128 * 128];  // 32 KB
  int t = threadIdx.x;
  // stage W: read row-major coalesced, write transposed + split + swizzled
  for (int idx = t; idx < 128 * 128; idx += 256) {
    int k = idx >> 7, n = idx & 127;
    float w = W[idx];
    _Float16 wh = (_Float16)w;
    _Float16 wl = (_Float16)(w - (float)wh);
    int e = n * 128 + (((k >> 3) ^ (n & 7)) << 3) + (k & 7);
    WtH[e] = wh;
    WtL[e] = wl;
  }
  __syncthreads();

  int wave = t >> 6, lane = t & 63;
  int mloc = wave >> 1;        // which m-tile of the block pair
  int nh = wave & 1;           // which 64-col half
  int l15 = lane & 15, lg = lane >> 4;

  // B fragments -> registers (4 n-tiles x 4 k-steps, hi+lo)
  f16x8 Bh[4][4], Bl[4][4];
  #pragma unroll
  for (int ntl = 0; ntl < 4; ++ntl) {
    int n = nh * 64 + ntl * 16 + l15;
    #pragma unroll
    for (int kk = 0; kk < 4; ++kk) {
      int k0 = kk * 32 + lg * 8;
      int e = n * 128 + (((k0 >> 3) ^ (n & 7)) << 3);
      Bh[ntl][kk] = *(const f16x8*)&WtH[e];
      Bl[ntl][kk] = *(const f16x8*)&WtL[e];
    }
  }

  for (int mt = blockIdx.x * 2 + mloc; mt < ntiles; mt += gridDim.x * 2) {
    int row = mt * 16 + l15;
    int rclamp = row < nrows ? row : (nrows - 1);
    const float* xr = X + (long)rclamp * FDIM;
    f32x4 acc[4] = {};
    #pragma unroll
    for (int kk = 0; kk < 4; ++kk) {
      int k0 = kk * 32 + lg * 8;
      float4 v0 = *(const float4*)(xr + k0);
      float4 v1 = *(const float4*)(xr + k0 + 4);
      float xv[8] = {v0.x, v0.y, v0.z, v0.w, v1.x, v1.y, v1.z, v1.w};
      f16x8 ah, al;
      #pragma unroll
      for (int j = 0; j < 8; ++j) {
        _Float16 hh = (_Float16)xv[j];
        ah[j] = hh;
        al[j] = (_Float16)(xv[j] - (float)hh);
      }
      #pragma unroll
      for (int ntl = 0; ntl < 4; ++ntl) {
        acc[ntl] = __builtin_amdgcn_mfma_f32_16x16x32_f16(ah, Bh[ntl][kk],
                                                          acc[ntl], 0, 0, 0);
        acc[ntl] = __builtin_amdgcn_mfma_f32_16x16x32_f16(ah, Bl[ntl][kk],
                                                          acc[ntl], 0, 0, 0);
        acc[ntl] = __builtin_amdgcn_mfma_f32_16x16x32_f16(al, Bh[ntl][kk],
                                                          acc[ntl], 0, 0, 0);
      }
    }
    // epilogue: C layout col=lane&15, row=(lane>>4)*4+reg
    #pragma unroll
    for (int ntl = 0; ntl < 4; ++ntl) {
      int c = nh * 64 + ntl * 16 + l15;
      #pragma unroll
      for (int r = 0; r < 4; ++r) {
        int rr = mt * 16 + lg * 4 + r;
        if (rr < nrows) Hh[(long)rr * FDIM + c] = __float2half(acc[ntl][r]);
      }
    }
  }
}

// ---------- attention coefficients from fp16 H ----------
__global__ void attn_coef_h_kernel(const __half2* __restrict__ Hh,  // [n][64]
                                   const float* __restrict__ att_s,
                                   const float* __restrict__ att_d,
                                   float* __restrict__ a_s,
                                   float* __restrict__ a_d, int n) {
  int idx = blockIdx.x * blockDim.x + threadIdx.x;  // n*HEADS
  if (idx >= n * HEADS) return;
  int node = idx >> 2, head = idx & 3;
  const __half2* hp = Hh + (long)node * 64 + head * 16;
  const float2* sp = (const float2*)(att_s + head * 32);
  const float2* dp = (const float2*)(att_d + head * 32);
  float ss = 0.f, sd = 0.f;
  #pragma unroll
  for (int c = 0; c < 16; ++c) {
    float2 v = __half22float2(hp[c]);
    float2 s2 = sp[c], d2 = dp[c];
    ss += v.x * s2.x + v.y * s2.y;
    sd += v.x * d2.x + v.y * d2.y;
  }
  a_s[idx] = ss;
  a_d[idx] = sd;
}

// ---------- fused GAT aggregation: one wave per destination node ----------
__global__ void gat_gather_kernel(const int* __restrict__ rowptr,
                                  const int* __restrict__ col,
                                  const __half2* __restrict__ Hh,  // [n][64]
                                  const float* __restrict__ a_s,
                                  const float* __restrict__ a_d,
                                  const float* __restrict__ bias,
                                  float* __restrict__ out,
                                  __half2* __restrict__ out_h,  // may be null
                                  int n, int do_silu) {
  int lane = threadIdx.x & 63;
  int node = blockIdx.x * (blockDim.x >> 6) + (threadIdx.x >> 6);
  if (node >= n) return;
  int beg = rowptr[node], end = rowptr[node + 1];
  int head = lane >> 4;
  float ad = a_d[(long)node * HEADS + head];
  float acc0 = 0.f, acc1 = 0.f, ssum = 0.f;
  int i = beg;
  for (; i + 4 <= end; i += 4) {
    int s0 = col[i], s1 = col[i + 1], s2 = col[i + 2], s3 = col[i + 3];
    float as0 = a_s[(long)s0 * HEADS + head];
    float as1 = a_s[(long)s1 * HEADS + head];
    float as2 = a_s[(long)s2 * HEADS + head];
    float as3 = a_s[(long)s3 * HEADS + head];
    __half2 h0 = Hh[(long)s0 * 64 + lane];
    __half2 h1 = Hh[(long)s1 * 64 + lane];
    __half2 h2 = Hh[(long)s2 * 64 + lane];
    __half2 h3 = Hh[(long)s3 * 64 + lane];
    float p0 = __expf(lrelu(as0 + ad));
    float p1 = __expf(lrelu(as1 + ad));
    float p2 = __expf(lrelu(as2 + ad));
    float p3 = __expf(lrelu(as3 + ad));
    float2 f0 = __half22float2(h0), f1 = __half22float2(h1);
    float2 f2 = __half22float2(h2), f3 = __half22float2(h3);
    acc0 += p0 * f0.x + p1 * f1.x + p2 * f2.x + p3 * f3.x;
    acc1 += p0 * f0.y + p1 * f1.y + p2 * f2.y + p3 * f3.y;
    ssum += p0 + p1 + p2 + p3;
  }
  for (; i < end; ++i) {
    int s = col[i];
    float as = a_s[(long)s * HEADS + head];
    __half2 hv = Hh[(long)s * 64 + lane];
    float p = __expf(lrelu(as + ad));
    float2 f = __half22float2(hv);
    acc0 += p * f.x;
    acc1 += p * f.y;
    ssum += p;
  }
  float inv = 1.f / (ssum + SM_EPS);
  float2 b2 = *(const float2*)(bias + 2 * lane);
  float o0 = acc0 * inv + b2.x;
  float o1 = acc1 * inv + b2.y;
  if (do_silu) {
    o0 = o0 / (1.f + __expf(-o0));
    o1 = o1 / (1.f + __expf(-o1));
  }
  *(float2*)(out + (long)node * FDIM + 2 * lane) = make_float2(o0, o1);
  if (out_h) out_h[(long)node * 64 + lane] = __floats2half2_rn(o0, o1);
}

// ---------- DistMult decoder (fp16 embeddings, f32 rel) ----------
__global__ void decoder_kernel(const __half2* __restrict__ emb_h,  // [n][64]
                               const float* __restrict__ rel_emb,
                               const int* __restrict__ hd,
                               const int* __restrict__ rl,
                               const int* __restrict__ tl,
                               float* __restrict__ out, int nq) {
  int lane = threadIdx.x & 63;
  int q = blockIdx.x * (blockDim.x >> 6) + (threadIdx.x >> 6);
  if (q >= nq) return;
  int h = hd[q], r = rl[q], t = tl[q];
  float2 eh = __half22float2(emb_h[(long)h * 64 + lane]);
  float2 et = __half22float2(emb_h[(long)t * 64 + lane]);
  float2 er = *(const float2*)(rel_emb + (long)r * FDIM + 2 * lane);
  float acc = eh.x * er.x * et.x + eh.y * er.y * et.y;
  #pragma unroll
  for (int off = 32; off > 0; off >>= 1) acc += __shfl_down(acc, off, 64);
  if (lane == 0) out[q] = 1.f / (1.f + __expf(-acc));
}

// ---------- host side ----------
extern "C" void kernel_launch(void* const* d_in, const int* in_sizes, int n_in,
                              void* d_out, int out_size, void* d_ws,
                              size_t ws_size, hipStream_t stream) {
  const float* x    = (const float*)d_in[0];
  const int*   esrc = (const int*)d_in[1];
  const int*   edst = (const int*)d_in[2];
  const int*   hidx = (const int*)d_in[3];
  const int*   rel  = (const int*)d_in[4];
  const int*   tidx = (const int*)d_in[5];
  const float* W1   = (const float*)d_in[6];
  const float* b1   = (const float*)d_in[7];
  const float* as1  = (const float*)d_in[8];
  const float* ad1  = (const float*)d_in[9];
  const float* W2   = (const float*)d_in[10];
  const float* b2   = (const float*)d_in[11];
  const float* as2  = (const float*)d_in[12];
  const float* ad2  = (const float*)d_in[13];
  const float* remb = (const float*)d_in[14];
  float* out = (float*)d_out;

  const int N_ = in_sizes[0] / FDIM;
  const int E_ = in_sizes[1];
  const int Q_ = in_sizes[3];

  // workspace layout
  float*   emb    = (float*)d_ws;                      // N*128 f32
  __half*  Hh     = (__half*)(emb + (long)N_ * FDIM);  // N*128 fp16
  __half*  emb_h  = Hh + (long)N_ * FDIM;              // N*128 fp16
  float*   a_s    = (float*)(emb_h + (long)N_ * FDIM); // N*4
  float*   a_d    = a_s + (long)N_ * HEADS;            // N*4
  int*     deg    = (int*)(a_d + (long)N_ * HEADS);    // N
  int*     fill   = deg + N_;                          // N
  int*     rowptr = fill + N_;                         // N+1
  int*     partials = rowptr + N_ + 1;                 // <=256
  int*     colsrc = partials + 256;                    // E

  // ---- build CSR (dst-sorted src list), reused by both layers ----
  zero_i_kernel<<<512, 256, 0, stream>>>(deg, 2L * N_);  // deg + fill
  hist_kernel<<<(E_ + 255) / 256, 256, 0, stream>>>(edst, deg, E_);
  int nb = (N_ + SCAN_CHUNK - 1) / SCAN_CHUNK;
  scan1_kernel<<<nb, SCAN_BLOCK, 0, stream>>>(deg, partials, N_);
  scan2_kernel<<<1, 64, 0, stream>>>(partials, nb);
  scan3_kernel<<<nb, SCAN_BLOCK, 0, stream>>>(deg, partials, rowptr, N_);
  scatter_kernel<<<(E_ + 255) / 256, 256, 0, stream>>>(esrc, edst, rowptr,
                                                       fill, colsrc, E_);

  const int ntiles = (N_ + 15) / 16;
  for (int layer = 0; layer < 2; ++layer) {
    const float* Xin  = (layer == 0) ? x : emb;
    const float* W    = (layer == 0) ? W1 : W2;
    const float* bias = (layer == 0) ? b1 : b2;
    const float* atts = (layer == 0) ? as1 : as2;
    const float* attd = (layer == 0) ? ad1 : ad2;

    mfma_linear_kernel<<<512, 256, 0, stream>>>(Xin, W, Hh, N_, ntiles);
    attn_coef_h_kernel<<<(N_ * HEADS + 255) / 256, 256, 0, stream>>>(
        (const __half2*)Hh, atts, attd, a_s, a_d, N_);
    gat_gather_kernel<<<(N_ + 3) / 4, 256, 0, stream>>>(
        rowptr, colsrc, (const __half2*)Hh, a_s, a_d, bias, emb,
        (layer == 1) ? (__half2*)emb_h : (__half2*)nullptr, N_,
        layer == 0 ? 1 : 0);
  }

  decoder_kernel<<<(Q_ + 3) / 4, 256, 0, stream>>>(
      (const __half2*)emb_h, remb, hidx, rel, tidx, out, Q_);
}

// Round 5
// 426.657 us; speedup vs baseline: 6.4482x; 1.1017x over previous
//
#include <hip/hip_runtime.h>
#include <hip/hip_fp16.h>

#define HEADS 4
#define FDIM 128          // HEADS * HID
#define NEG_SLOPE 0.2f
#define SM_EPS 1e-16f

typedef _Float16 f16x8 __attribute__((ext_vector_type(8)));
typedef float f32x4 __attribute__((ext_vector_type(4)));

__device__ __forceinline__ float lrelu(float v) {
  return v >= 0.f ? v : NEG_SLOPE * v;
}

// ---------- zero fill (ints) ----------
__global__ void zero_i_kernel(int* __restrict__ p, long n) {
  long i = (long)blockIdx.x * blockDim.x + threadIdx.x;
  long stride = (long)gridDim.x * blockDim.x;
  for (; i < n; i += stride) p[i] = 0;
}

// ---------- CSR build: XCD-ranged degree histogram ----------
// block b: dst-range (b&7)  [XCD heuristic: blockIdx%8 -> XCD], chunk b>>3.
// All atomics on deg[lo..hi) come from one XCD -> RMW lines stay in local L2.
__global__ void hist_ranged_kernel(const int* __restrict__ dst,
                                   int* __restrict__ deg, int ne, int n) {
  int r = blockIdx.x & 7;
  int nchunks = gridDim.x >> 3;
  int chunk = blockIdx.x >> 3;
  int rngsz = (n + 7) >> 3;
  int lo = r * rngsz;
  int hi = min(n, lo + rngsz);
  long per = ((long)ne + nchunks - 1) / nchunks;
  long beg = (long)chunk * per;
  long end = min((long)ne, beg + per);
  for (long i = beg + threadIdx.x; i < end; i += blockDim.x) {
    int d = dst[i];
    if (d >= lo && d < hi) atomicAdd(&deg[d], 1);
  }
}

// ---------- 3-phase exclusive scan over deg[n] -> rowptr[n+1] ----------
#define SCAN_BLOCK 256
#define SCAN_CHUNK 1024  // 4 elems / thread

__global__ void scan1_kernel(const int* __restrict__ deg,
                             int* __restrict__ partials, int n) {
  __shared__ int sdata[SCAN_BLOCK];
  int chunk0 = blockIdx.x * SCAN_CHUNK;
  int t = threadIdx.x;
  int sum = 0;
  #pragma unroll
  for (int j = 0; j < 4; ++j) {
    int idx = chunk0 + t * 4 + j;
    if (idx < n) sum += deg[idx];
  }
  sdata[t] = sum;
  __syncthreads();
  for (int off = SCAN_BLOCK / 2; off > 0; off >>= 1) {
    if (t < off) sdata[t] += sdata[t + off];
    __syncthreads();
  }
  if (t == 0) partials[blockIdx.x] = sdata[0];
}

__global__ void scan2_kernel(int* __restrict__ partials, int nb) {
  if (threadIdx.x == 0 && blockIdx.x == 0) {
    int run = 0;
    for (int i = 0; i < nb; ++i) {
      int v = partials[i];
      partials[i] = run;
      run += v;
    }
  }
}

__global__ void scan3_kernel(const int* __restrict__ deg,
                             const int* __restrict__ partials,
                             int* __restrict__ rowptr, int n) {
  __shared__ int sdata[SCAN_BLOCK];
  int chunk0 = blockIdx.x * SCAN_CHUNK;
  int t = threadIdx.x;
  int v[4];
  int sum = 0;
  #pragma unroll
  for (int j = 0; j < 4; ++j) {
    int idx = chunk0 + t * 4 + j;
    v[j] = (idx < n) ? deg[idx] : 0;
    sum += v[j];
  }
  sdata[t] = sum;
  __syncthreads();
  for (int off = 1; off < SCAN_BLOCK; off <<= 1) {
    int val = sdata[t];
    int add = (t >= off) ? sdata[t - off] : 0;
    __syncthreads();
    sdata[t] = val + add;
    __syncthreads();
  }
  int ex = (t > 0) ? sdata[t - 1] : 0;
  int base = partials[blockIdx.x] + ex;
  #pragma unroll
  for (int j = 0; j < 4; ++j) {
    int idx = chunk0 + t * 4 + j;
    if (idx < n) {
      rowptr[idx] = base;
      base += v[j];
      if (idx == n - 1) rowptr[n] = base;
    }
  }
}

// ---------- CSR build: XCD-ranged scatter of src indices ----------
// Same range/chunk decomposition as hist: writes into col[] segment for
// range r come only from XCD r -> lines merge in local L2 instead of
// ping-ponging across XCDs (R3 counter: 110 MB HBM write for 6.4 MB payload).
__global__ void scatter_ranged_kernel(const int* __restrict__ src,
                                      const int* __restrict__ dst,
                                      const int* __restrict__ rowptr,
                                      int* __restrict__ fill,
                                      int* __restrict__ col, int ne, int n) {
  int r = blockIdx.x & 7;
  int nchunks = gridDim.x >> 3;
  int chunk = blockIdx.x >> 3;
  int rngsz = (n + 7) >> 3;
  int lo = r * rngsz;
  int hi = min(n, lo + rngsz);
  long per = ((long)ne + nchunks - 1) / nchunks;
  long beg = (long)chunk * per;
  long end = min((long)ne, beg + per);
  for (long i = beg + threadIdx.x; i < end; i += blockDim.x) {
    int d = dst[i];
    if (d >= lo && d < hi) {
      int pos = rowptr[d] + atomicAdd(&fill[d], 1);
      col[pos] = src[i];
    }
  }
}

// ---------- MFMA split-fp16 linear + fused attention coefficients ----------
// Hh[n,128] = f16(X @ W) via xh*wh + xh*wl + xl*wh (f32 accum).
// Epilogue also produces a_s[n,4], a_d[n,4]: each wave holds 64 cols of its
// 16 rows in acc; 16-lane shfl_xor reduce -> exactly one writer per entry.
__global__ __launch_bounds__(256) void mfma_linear_kernel(
    const float* __restrict__ X, const float* __restrict__ W,
    const float* __restrict__ att_s, const float* __restrict__ att_d,
    __half* __restrict__ Hh, float* __restrict__ a_s, float* __restrict__ a_d,
    int nrows, int ntiles) {
  __shared__ _Float16 WtH[128 * 128];  // 32 KB
  __shared__ _Float16 WtL[128 * 128];  // 32 KB
  int t = threadIdx.x;
  for (int idx = t; idx < 128 * 128; idx += 256) {
    int k = idx >> 7, n = idx & 127;
    float w = W[idx];
    _Float16 wh = (_Float16)w;
    _Float16 wl = (_Float16)(w - (float)wh);
    int e = n * 128 + (((k >> 3) ^ (n & 7)) << 3) + (k & 7);
    WtH[e] = wh;
    WtL[e] = wl;
  }
  __syncthreads();

  int wave = t >> 6, lane = t & 63;
  int mloc = wave >> 1;  // which m-tile of the block pair
  int nh = wave & 1;     // which 64-col half
  int l15 = lane & 15, lg = lane >> 4;

  // B fragments -> registers (4 n-tiles x 4 k-steps, hi+lo)
  f16x8 Bh[4][4], Bl[4][4];
  float ws[4], wd[4];
  #pragma unroll
  for (int ntl = 0; ntl < 4; ++ntl) {
    int n = nh * 64 + ntl * 16 + l15;
    ws[ntl] = att_s[n];
    wd[ntl] = att_d[n];
    #pragma unroll
    for (int kk = 0; kk < 4; ++kk) {
      int k0 = kk * 32 + lg * 8;
      int e = n * 128 + (((k0 >> 3) ^ (n & 7)) << 3);
      Bh[ntl][kk] = *(const f16x8*)&WtH[e];
      Bl[ntl][kk] = *(const f16x8*)&WtL[e];
    }
  }

  for (int mt = blockIdx.x * 2 + mloc; mt < ntiles; mt += gridDim.x * 2) {
    int row = mt * 16 + l15;
    int rclamp = row < nrows ? row : (nrows - 1);
    const float* xr = X + (long)rclamp * FDIM;
    f32x4 acc[4] = {};
    #pragma unroll
    for (int kk = 0; kk < 4; ++kk) {
      int k0 = kk * 32 + lg * 8;
      float4 v0 = *(const float4*)(xr + k0);
      float4 v1 = *(const float4*)(xr + k0 + 4);
      float xv[8] = {v0.x, v0.y, v0.z, v0.w, v1.x, v1.y, v1.z, v1.w};
      f16x8 ah, al;
      #pragma unroll
      for (int j = 0; j < 8; ++j) {
        _Float16 hh = (_Float16)xv[j];
        ah[j] = hh;
        al[j] = (_Float16)(xv[j] - (float)hh);
      }
      #pragma unroll
      for (int ntl = 0; ntl < 4; ++ntl) {
        acc[ntl] = __builtin_amdgcn_mfma_f32_16x16x32_f16(ah, Bh[ntl][kk],
                                                          acc[ntl], 0, 0, 0);
        acc[ntl] = __builtin_amdgcn_mfma_f32_16x16x32_f16(ah, Bl[ntl][kk],
                                                          acc[ntl], 0, 0, 0);
        acc[ntl] = __builtin_amdgcn_mfma_f32_16x16x32_f16(al, Bh[ntl][kk],
                                                          acc[ntl], 0, 0, 0);
      }
    }
    // epilogue: C layout col=lane&15, row=(lane>>4)*4+reg
    #pragma unroll
    for (int r = 0; r < 4; ++r) {
      int rr = mt * 16 + lg * 4 + r;
      #pragma unroll
      for (int ntl = 0; ntl < 4; ++ntl) {
        int c = nh * 64 + ntl * 16 + l15;
        if (rr < nrows) Hh[(long)rr * FDIM + c] = __float2half(acc[ntl][r]);
      }
      // attention coefficients: heads 2*nh (ntl 0,1) and 2*nh+1 (ntl 2,3)
      float vs0 = acc[0][r] * ws[0] + acc[1][r] * ws[1];
      float vs1 = acc[2][r] * ws[2] + acc[3][r] * ws[3];
      float vd0 = acc[0][r] * wd[0] + acc[1][r] * wd[1];
      float vd1 = acc[2][r] * wd[2] + acc[3][r] * wd[3];
      #pragma unroll
      for (int off = 8; off >= 1; off >>= 1) {
        vs0 += __shfl_xor(vs0, off, 64);
        vs1 += __shfl_xor(vs1, off, 64);
        vd0 += __shfl_xor(vd0, off, 64);
        vd1 += __shfl_xor(vd1, off, 64);
      }
      if (l15 == 0 && rr < nrows) {
        a_s[(long)rr * HEADS + nh * 2] = vs0;
        a_s[(long)rr * HEADS + nh * 2 + 1] = vs1;
        a_d[(long)rr * HEADS + nh * 2] = vd0;
        a_d[(long)rr * HEADS + nh * 2 + 1] = vd1;
      }
    }
  }
}

// ---------- fused GAT aggregation: one wave per destination node ----------
__global__ void gat_gather_kernel(const int* __restrict__ rowptr,
                                  const int* __restrict__ col,
                                  const __half2* __restrict__ Hh,  // [n][64]
                                  const float* __restrict__ a_s,
                                  const float* __restrict__ a_d,
                                  const float* __restrict__ bias,
                                  float* __restrict__ out,
                                  __half2* __restrict__ out_h,  // may be null
                                  int n, int do_silu) {
  int lane = threadIdx.x & 63;
  int node = blockIdx.x * (blockDim.x >> 6) + (threadIdx.x >> 6);
  if (node >= n) return;
  int beg = rowptr[node], end = rowptr[node + 1];
  int head = lane >> 4;
  float ad = a_d[(long)node * HEADS + head];
  float acc0 = 0.f, acc1 = 0.f, ssum = 0.f;
  int i = beg;
  for (; i + 4 <= end; i += 4) {
    int s0 = col[i], s1 = col[i + 1], s2 = col[i + 2], s3 = col[i + 3];
    float as0 = a_s[(long)s0 * HEADS + head];
    float as1 = a_s[(long)s1 * HEADS + head];
    float as2 = a_s[(long)s2 * HEADS + head];
    float as3 = a_s[(long)s3 * HEADS + head];
    __half2 h0 = Hh[(long)s0 * 64 + lane];
    __half2 h1 = Hh[(long)s1 * 64 + lane];
    __half2 h2 = Hh[(long)s2 * 64 + lane];
    __half2 h3 = Hh[(long)s3 * 64 + lane];
    float p0 = __expf(lrelu(as0 + ad));
    float p1 = __expf(lrelu(as1 + ad));
    float p2 = __expf(lrelu(as2 + ad));
    float p3 = __expf(lrelu(as3 + ad));
    float2 f0 = __half22float2(h0), f1 = __half22float2(h1);
    float2 f2 = __half22float2(h2), f3 = __half22float2(h3);
    acc0 += p0 * f0.x + p1 * f1.x + p2 * f2.x + p3 * f3.x;
    acc1 += p0 * f0.y + p1 * f1.y + p2 * f2.y + p3 * f3.y;
    ssum += p0 + p1 + p2 + p3;
  }
  for (; i < end; ++i) {
    int s = col[i];
    float as = a_s[(long)s * HEADS + head];
    __half2 hv = Hh[(long)s * 64 + lane];
    float p = __expf(lrelu(as + ad));
    float2 f = __half22float2(hv);
    acc0 += p * f.x;
    acc1 += p * f.y;
    ssum += p;
  }
  float inv = 1.f / (ssum + SM_EPS);
  float2 b2 = *(const float2*)(bias + 2 * lane);
  float o0 = acc0 * inv + b2.x;
  float o1 = acc1 * inv + b2.y;
  if (do_silu) {
    o0 = o0 / (1.f + __expf(-o0));
    o1 = o1 / (1.f + __expf(-o1));
  }
  *(float2*)(out + (long)node * FDIM + 2 * lane) = make_float2(o0, o1);
  if (out_h) out_h[(long)node * 64 + lane] = __floats2half2_rn(o0, o1);
}

// ---------- DistMult decoder (fp16 embeddings, f32 rel) ----------
__global__ void decoder_kernel(const __half2* __restrict__ emb_h,  // [n][64]
                               const float* __restrict__ rel_emb,
                               const int* __restrict__ hd,
                               const int* __restrict__ rl,
                               const int* __restrict__ tl,
                               float* __restrict__ out, int nq) {
  int lane = threadIdx.x & 63;
  int q = blockIdx.x * (blockDim.x >> 6) + (threadIdx.x >> 6);
  if (q >= nq) return;
  int h = hd[q], r = rl[q], t = tl[q];
  float2 eh = __half22float2(emb_h[(long)h * 64 + lane]);
  float2 et = __half22float2(emb_h[(long)t * 64 + lane]);
  float2 er = *(const float2*)(rel_emb + (long)r * FDIM + 2 * lane);
  float acc = eh.x * er.x * et.x + eh.y * er.y * et.y;
  #pragma unroll
  for (int off = 32; off > 0; off >>= 1) acc += __shfl_down(acc, off, 64);
  if (lane == 0) out[q] = 1.f / (1.f + __expf(-acc));
}

// ---------- host side ----------
extern "C" void kernel_launch(void* const* d_in, const int* in_sizes, int n_in,
                              void* d_out, int out_size, void* d_ws,
                              size_t ws_size, hipStream_t stream) {
  const float* x    = (const float*)d_in[0];
  const int*   esrc = (const int*)d_in[1];
  const int*   edst = (const int*)d_in[2];
  const int*   hidx = (const int*)d_in[3];
  const int*   rel  = (const int*)d_in[4];
  const int*   tidx = (const int*)d_in[5];
  const float* W1   = (const float*)d_in[6];
  const float* b1   = (const float*)d_in[7];
  const float* as1  = (const float*)d_in[8];
  const float* ad1  = (const float*)d_in[9];
  const float* W2   = (const float*)d_in[10];
  const float* b2   = (const float*)d_in[11];
  const float* as2  = (const float*)d_in[12];
  const float* ad2  = (const float*)d_in[13];
  const float* remb = (const float*)d_in[14];
  float* out = (float*)d_out;

  const int N_ = in_sizes[0] / FDIM;
  const int E_ = in_sizes[1];
  const int Q_ = in_sizes[3];

  // workspace layout
  float*   emb    = (float*)d_ws;                      // N*128 f32
  __half*  Hh     = (__half*)(emb + (long)N_ * FDIM);  // N*128 fp16
  __half*  emb_h  = Hh + (long)N_ * FDIM;              // N*128 fp16
  float*   a_s    = (float*)(emb_h + (long)N_ * FDIM); // N*4
  float*   a_d    = a_s + (long)N_ * HEADS;            // N*4
  int*     deg    = (int*)(a_d + (long)N_ * HEADS);    // N
  int*     fill   = deg + N_;                          // N
  int*     rowptr = fill + N_;                         // N+1
  int*     partials = rowptr + N_ + 1;                 // <=256
  int*     colsrc = partials + 256;                    // E

  // ---- build CSR (dst-sorted src list), reused by both layers ----
  zero_i_kernel<<<512, 256, 0, stream>>>(deg, 2L * N_);  // deg + fill
  hist_ranged_kernel<<<512, 256, 0, stream>>>(edst, deg, E_, N_);
  int nb = (N_ + SCAN_CHUNK - 1) / SCAN_CHUNK;
  scan1_kernel<<<nb, SCAN_BLOCK, 0, stream>>>(deg, partials, N_);
  scan2_kernel<<<1, 64, 0, stream>>>(partials, nb);
  scan3_kernel<<<nb, SCAN_BLOCK, 0, stream>>>(deg, partials, rowptr, N_);
  scatter_ranged_kernel<<<512, 256, 0, stream>>>(esrc, edst, rowptr, fill,
                                                 colsrc, E_, N_);

  const int ntiles = (N_ + 15) / 16;
  for (int layer = 0; layer < 2; ++layer) {
    const float* Xin  = (layer == 0) ? x : emb;
    const float* W    = (layer == 0) ? W1 : W2;
    const float* bias = (layer == 0) ? b1 : b2;
    const float* atts = (layer == 0) ? as1 : as2;
    const float* attd = (layer == 0) ? ad1 : ad2;

    mfma_linear_kernel<<<512, 256, 0, stream>>>(Xin, W, atts, attd, Hh, a_s,
                                                a_d, N_, ntiles);
    gat_gather_kernel<<<(N_ + 3) / 4, 256, 0, stream>>>(
        rowptr, colsrc, (const __half2*)Hh, a_s, a_d, bias, emb,
        (layer == 1) ? (__half2*)emb_h : (__half2*)nullptr, N_,
        layer == 0 ? 1 : 0);
  }

  decoder_kernel<<<(Q_ + 3) / 4, 256, 0, stream>>>(
      (const __half2*)emb_h, remb, hidx, rel, tidx, out, Q_);
}